// Round 5
// baseline (440.540 us; speedup 1.0000x reference)
//
#include <hip/hip_runtime.h>
#include <cstdint>
#include <cstddef>
#include <cmath>

typedef __bf16 bf16_t;
typedef __bf16 bf16x8 __attribute__((ext_vector_type(8)));
typedef float floatx4 __attribute__((ext_vector_type(4)));

#define AS1 __attribute__((address_space(1)))
#define AS3 __attribute__((address_space(3)))

__device__ __forceinline__ void gload_lds16(const bf16_t* g, bf16_t* l) {
    __builtin_amdgcn_global_load_lds((AS1 void*)(uintptr_t)(g), (AS3 void*)(l), 16, 0, 0);
}

__device__ __forceinline__ float sigf(float x) { return 1.0f / (1.0f + __expf(-x)); }
__device__ __forceinline__ float tanhfast(float x) { return 1.0f - 2.0f / (__expf(2.0f * x) + 1.0f); }

// ------------- Fused GEMM + LSTM cell (templated M-tile) -------------
// gates(M x N) = A(M,K) @ W(N,K)^T + bias(N), then LSTM cell per element.
// Weight rows packed gate-interleaved: each lane's acc[i][0..3] are the 4
// gates (i,f,g,o) of one element column e = ((n0+wn)>>2)+(lane&15).
// LDS XOR swizzle: physical 16B chunk = logical_kchunk ^ (row&7); staging
// keeps the mandatory linear base+lane*16 global_load_lds pattern by
// permuting the per-lane *global* address (still intra-128B-segment coalesced).
// Proven 2-barrier m97-structure (51 us/enc-layer @ K=1152, 4 blocks/CU);
// R2's 8-phase port regressed (lockstep waves) and stays reverted.
// czero=1: c-in is exactly zero -> skip the c load (layer 0).
template<int BM>
__global__ __launch_bounds__(256, 4)
void gemm_lstm(const bf16_t* __restrict__ A, const bf16_t* __restrict__ B,
               const float* __restrict__ bias,
               float* __restrict__ c, int EP,
               bf16_t* __restrict__ hb, int ldH, int hoff,
               int K, int ldA, int ldB, int relu, int czero)
{
    constexpr int AI = BM / 32;          // i-frags per wave = A-chunks per thread
    __shared__ bf16_t As[BM * 64];
    __shared__ bf16_t Bs[128 * 64];
    const int tid  = threadIdx.x;
    const int lane = tid & 63;
    const int w    = tid >> 6;
    const int wm   = (w & 1) * (BM / 2);
    const int wn   = (w >> 1) * 64;
    const int m0   = blockIdx.y * BM;
    const int n0   = blockIdx.x * 128;

    floatx4 zero = {0.0f, 0.0f, 0.0f, 0.0f};
    floatx4 acc[AI][4];
#pragma unroll
    for (int i = 0; i < AI; ++i)
#pragma unroll
        for (int j = 0; j < 4; ++j) acc[i][j] = zero;

    const int srow = lane >> 3;                 // staging row-in-chunk 0..7
    const int sk   = ((lane & 7) ^ srow) * 8;   // swizzled k-chunk (elements)
    const int fr   = lane & 15;                 // fragment row
    const int fx   = fr & 7;                    // read-side xor key

    const bf16_t* Ag = A + (size_t)(m0 + srow) * ldA + sk;
    const bf16_t* Bg = B + (size_t)(n0 + srow) * ldB + sk;

    for (int k0 = 0; k0 < K; k0 += 64) {
        __syncthreads();
#pragma unroll
        for (int j = 0; j < AI; ++j) {
            int r0 = (w * AI + j) * 8;
            gload_lds16(Ag + (size_t)r0 * ldA + k0, As + r0 * 64 + lane * 8);
        }
#pragma unroll
        for (int j = 0; j < 4; ++j) {
            int r0 = (w * 4 + j) * 8;
            gload_lds16(Bg + (size_t)r0 * ldB + k0, Bs + r0 * 64 + lane * 8);
        }
        __syncthreads();
#pragma unroll
        for (int kk = 0; kk < 64; kk += 32) {
            const int pc = ((((kk >> 3) + (lane >> 4)) ^ fx) << 3);
            bf16x8 af[AI], bfr[4];
#pragma unroll
            for (int i = 0; i < AI; ++i)
                af[i] = *(const bf16x8*)(As + (wm + i * 16 + fr) * 64 + pc);
#pragma unroll
            for (int j = 0; j < 4; ++j)
                bfr[j] = *(const bf16x8*)(Bs + (wn + j * 16 + fr) * 64 + pc);
#pragma unroll
            for (int i = 0; i < AI; ++i)
#pragma unroll
                for (int j = 0; j < 4; ++j)
                    acc[i][j] = __builtin_amdgcn_mfma_f32_16x16x32_bf16(af[i], bfr[j], acc[i][j], 0, 0, 0);
        }
    }

    // Epilogue. C/D layout: col = lane&15, row = (lane>>4)*4 + reg.
    const int crow = (lane >> 4) * 4;
    const int ccol = lane & 15;
    const int nn   = n0 + wn;
    float bi[4];
#pragma unroll
    for (int j = 0; j < 4; ++j) bi[j] = bias[nn + j * 16 + ccol];

    const int e = (nn >> 2) + ccol;
#pragma unroll
    for (int i = 0; i < AI; ++i) {
#pragma unroll
        for (int r = 0; r < 4; ++r) {
            int t = m0 + wm + i * 16 + crow + r;
            float g0 = acc[i][0][r] + bi[0];
            float g1 = acc[i][1][r] + bi[1];
            float g2 = acc[i][2][r] + bi[2];
            float g3 = acc[i][3][r] + bi[3];
            size_t cix = (size_t)t * EP + e;
            float cold = 0.0f;
            if (!czero) cold = c[cix];
            float cv = sigf(g1) * cold + sigf(g0) * tanhfast(g2);
            c[cix] = cv;
            float hv = sigf(g3) * tanhfast(cv);
            if (relu) hv = fmaxf(hv, 0.0f);
            hb[(size_t)t * ldH + hoff + e] = (bf16_t)hv;
        }
    }
}

// ========= Fully-fused decoder: Z-in-registers + 4 layers + log_softmax =========
// R4's Z-GEMM (bad shape: 512 blocks @ 2/CU, ~50us) and dec_fused's
// latency-bound Z gathers are replaced by ONE kernel where Z never touches
// memory. Block = 32 rows (grid 128). Wave w computes the 16 n-frags
// {l*512 + w*64 + j*16} (l=0..3, j=0..3): packed position p = w*64+j*16+ccol
// gives gate g=(p>>4)&3=j and e=(p>>6)*16+ccol = w*16+ccol -- so each wave
// holds the 4 gates of its OWN e-group for EVERY layer, entirely in
// registers: acc[i][l][j] (i = 16-row half), 128 f32/lane.
//   Z-phase : A-tile (32x1024 bf16) in LDS (pad-1032: fragment rows land
//             2-way on banks = free), W streamed from L2 (B-frag shared by
//             both i-halves -> 512 MFMA-pairs, 512 loads per wave).
//   bias    : added into acc (same value chain as the unfused path).
//   layers  : l=0 pure cell; l>0 adds h@Whh_l^T via MFMA with acc as C-in
//             (same k-ascending accumulation order as before -> numerics
//             unchanged). h round-trips through LDS bf16 (pad-136).
//   softmax : layer-3 h in f32 LDS -> log_softmax over 101 cols -> out.
// W L2 traffic: 128 blocks x 4 MB = 512 MB (~16 blocks/XCD vs 4 MB L2).
__global__ __launch_bounds__(512, 2)
void dec_fused2(const bf16_t* __restrict__ Adec, const bf16_t* __restrict__ Wd,
                const float* __restrict__ bsd, float* __restrict__ out)
{
    __shared__ bf16_t hA[32 * 1032];   // 66.0 KB  enc-h A-tile
    __shared__ bf16_t hB[32 * 136];    //  8.7 KB  inter-layer h
    __shared__ float  hS[32 * 132];    // 16.9 KB  layer-3 h for softmax
    const int tid  = threadIdx.x;
    const int lane = tid & 63;
    const int w    = tid >> 6;         // 0..7
    const int m0   = blockIdx.x * 32;
    const int fr   = lane & 15;        // A-frag row / B-frag row (= ccol)
    const int ksl  = (lane >> 4) * 8;  // k-slice offset
    const int crow = (lane >> 4) * 4;

    // ---- stage A: 32 rows x 1024 cols (128 chunks of 8 bf16 per row) ----
    for (int u = tid; u < 4096; u += 512) {
        int r = u >> 7, c8 = u & 127;
        *(bf16x8*)(hA + r * 1032 + c8 * 8) =
            *(const bf16x8*)(Adec + (size_t)(m0 + r) * 1152 + c8 * 8);
    }
    __syncthreads();

    floatx4 zerov = {0.0f, 0.0f, 0.0f, 0.0f};
    floatx4 acc[2][4][4];              // [i-half][layer][gate]
#pragma unroll
    for (int i = 0; i < 2; ++i)
#pragma unroll
        for (int l = 0; l < 4; ++l)
#pragma unroll
            for (int j = 0; j < 4; ++j) acc[i][l][j] = zerov;

    // ---- Z-phase: acc += A(32x1024) @ dWih-part^T (K=1024, 32 kk-steps) ----
#pragma unroll 4
    for (int kk = 0; kk < 32; ++kk) {
        bf16x8 a0 = *(const bf16x8*)(hA + fr * 1032 + kk * 32 + ksl);
        bf16x8 a1 = *(const bf16x8*)(hA + (16 + fr) * 1032 + kk * 32 + ksl);
#pragma unroll
        for (int l = 0; l < 4; ++l)
#pragma unroll
            for (int j = 0; j < 4; ++j) {
                bf16x8 b = *(const bf16x8*)(Wd +
                    (size_t)(l * 512 + w * 64 + j * 16 + fr) * 1152 + kk * 32 + ksl);
                acc[0][l][j] = __builtin_amdgcn_mfma_f32_16x16x32_bf16(a0, b, acc[0][l][j], 0, 0, 0);
                acc[1][l][j] = __builtin_amdgcn_mfma_f32_16x16x32_bf16(a1, b, acc[1][l][j], 0, 0, 0);
            }
    }

    // ---- + bias (bsd is per packed n-position, incl. both bih+bhh) ----
#pragma unroll
    for (int l = 0; l < 4; ++l)
#pragma unroll
        for (int j = 0; j < 4; ++j) {
            float bi = bsd[l * 512 + w * 64 + j * 16 + fr];
            acc[0][l][j] += bi;
            acc[1][l][j] += bi;
        }

    // ---- 4 decoder layers; c in registers, h via LDS ----
    float cst[2][4];
    for (int l = 0; l < 4; ++l) {
        if (l > 0) {
            // acc[.][l][.] += h(32x128) @ dWhh_l^T  (K=128, 4 kk-steps)
            bf16x8 a2[4][2];
#pragma unroll
            for (int kk = 0; kk < 4; ++kk) {
                a2[kk][0] = *(const bf16x8*)(hB + fr * 136 + kk * 32 + ksl);
                a2[kk][1] = *(const bf16x8*)(hB + (16 + fr) * 136 + kk * 32 + ksl);
            }
#pragma unroll
            for (int kk = 0; kk < 4; ++kk)
#pragma unroll
                for (int j = 0; j < 4; ++j) {
                    bf16x8 b = *(const bf16x8*)(Wd +
                        (size_t)(l * 512 + w * 64 + j * 16 + fr) * 1152 + 1024 + kk * 32 + ksl);
                    acc[0][l][j] = __builtin_amdgcn_mfma_f32_16x16x32_bf16(a2[kk][0], b, acc[0][l][j], 0, 0, 0);
                    acc[1][l][j] = __builtin_amdgcn_mfma_f32_16x16x32_bf16(a2[kk][1], b, acc[1][l][j], 0, 0, 0);
                }
            __syncthreads();   // hB reads complete before overwrite below
        }
#pragma unroll
        for (int i = 0; i < 2; ++i)
#pragma unroll
            for (int r = 0; r < 4; ++r) {
                float g0 = acc[i][l][0][r];
                float g1 = acc[i][l][1][r];
                float g2 = acc[i][l][2][r];
                float g3 = acc[i][l][3][r];
                float cold = (l == 0) ? 0.0f : cst[i][r];
                float cv = sigf(g1) * cold + sigf(g0) * tanhfast(g2);
                cst[i][r] = cv;
                float hv = sigf(g3) * tanhfast(cv);
                int row = i * 16 + crow + r;
                int e   = w * 16 + fr;
                if (l < 3) hB[row * 136 + e] = (bf16_t)hv;
                else       hS[row * 132 + e] = hv;
            }
        __syncthreads();       // h fully written before next layer / softmax
    }

    // ---- fused log_softmax over 101 valid cols: wave w rows w*4..w*4+3 ----
#pragma unroll
    for (int rr = 0; rr < 4; ++rr) {
        int row = w * 4 + rr;
        const float* hr = hS + row * 132;
        float v1 = (lane < 101)      ? hr[lane]      : -INFINITY;
        float v2 = (lane + 64 < 101) ? hr[lane + 64] : -INFINITY;
        float m = fmaxf(v1, v2);
#pragma unroll
        for (int off = 32; off > 0; off >>= 1) m = fmaxf(m, __shfl_down(m, off));
        m = __shfl(m, 0);
        float ev = ((lane < 101) ? __expf(v1 - m) : 0.0f)
                 + ((lane + 64 < 101) ? __expf(v2 - m) : 0.0f);
#pragma unroll
        for (int off = 32; off > 0; off >>= 1) ev += __shfl_down(ev, off);
        float lse = m + __logf(__shfl(ev, 0));
        float* orow = out + (size_t)(m0 + row) * 101;
        if (lane < 101)      orow[lane]      = v1 - lse;
        if (lane + 64 < 101) orow[lane + 64] = v2 - lse;
    }
}

// ---------------- Packing (interleaved-gate layout, vectorized) ----------------
// A_enc (4096 x 1152 bf16): [x(0:101) pad(101:128) h(128:1152)]
// A_dec (4096 x 1152 bf16): [enc(0:1024) h-slot unused]
// One kernel, block-range dispatched (all outputs disjoint):
//   [0,     9216) : W_enc  (16384 rows * 144 groups of 8)
//   [9216, 11520) : A_enc x+zero fill (4096 rows * 144 groups)
//   [11520,12672) : W_dec  (2048 rows * 144 groups)
//   [12672,12744) : biases (16384 enc + 2048 dec)
// Layer-0 K-trim + czero keep every buffer write-before-read
// (ws re-poisoned 0xAA every call).
__global__ void pack_all(const float* __restrict__ x,
                         const float* __restrict__ eWih, const float* __restrict__ eWhh,
                         const float* __restrict__ ebih, const float* __restrict__ ebhh,
                         const float* __restrict__ dWih, const float* __restrict__ dWhh,
                         const float* __restrict__ dbih, const float* __restrict__ dbhh,
                         bf16_t* __restrict__ Aenc, bf16_t* __restrict__ Wenc,
                         bf16_t* __restrict__ Wdec,
                         float* __restrict__ bse, float* __restrict__ bsd)
{
    const int b = blockIdx.x;
    if (b < 9216) {
        int gid = b * 256 + threadIdx.x;
        int row = gid / 144, grp = gid - row * 144;
        int l = row >> 12, p = row & 4095;
        int g = (p >> 4) & 3, e = ((p >> 6) << 4) + (p & 15);
        int c0 = grp * 8;
        float v[8];
#pragma unroll
        for (int u = 0; u < 8; ++u) v[u] = 0.0f;
        if (e < 1000) {
            size_t r = (size_t)l * 4000 + g * 1000 + e;
            if (c0 >= 128 && c0 < 1128) {
                const float* src = eWhh + r * 1000 + (c0 - 128);
                float4 a = *(const float4*)src;
                float4 bq = *(const float4*)(src + 4);
                v[0]=a.x; v[1]=a.y; v[2]=a.z; v[3]=a.w; v[4]=bq.x; v[5]=bq.y; v[6]=bq.z; v[7]=bq.w;
            } else if (c0 < 128) {
                const float* src = eWih + r * 101;
#pragma unroll
                for (int u = 0; u < 8; ++u) { int cc = c0 + u; if (cc < 101) v[u] = src[cc]; }
            }
        }
        bf16x8 o;
#pragma unroll
        for (int u = 0; u < 8; ++u) o[u] = (bf16_t)v[u];
        *(bf16x8*)(Wenc + (size_t)row * 1152 + c0) = o;
    } else if (b < 11520) {
        int gid = (b - 9216) * 256 + threadIdx.x;
        int row = gid / 144, grp = gid - row * 144;
        int c0  = grp * 8;
        float v[8];
#pragma unroll
        for (int u = 0; u < 8; ++u) v[u] = 0.0f;
        if (c0 < 101) {
            const float* src = x + (size_t)row * 101;
#pragma unroll
            for (int u = 0; u < 8; ++u) { int cc = c0 + u; if (cc < 101) v[u] = src[cc]; }
        }
        bf16x8 o;
#pragma unroll
        for (int u = 0; u < 8; ++u) o[u] = (bf16_t)v[u];
        *(bf16x8*)(Aenc + (size_t)row * 1152 + c0) = o;
    } else if (b < 12672) {
        int gid = (b - 11520) * 256 + threadIdx.x;
        int row = gid / 144, grp = gid - row * 144;
        int l = row >> 9, p = row & 511;
        int g = (p >> 4) & 3, e = ((p >> 6) << 4) + (p & 15);
        int c0 = grp * 8;
        float v[8];
#pragma unroll
        for (int u = 0; u < 8; ++u) v[u] = 0.0f;
        if (e < 101) {
            size_t r = (size_t)l * 404 + g * 101 + e;
            if (c0 < 1000) {
                const float* src = dWih + r * 1000 + c0;
                float4 a = *(const float4*)src;
                float4 bq = *(const float4*)(src + 4);
                v[0]=a.x; v[1]=a.y; v[2]=a.z; v[3]=a.w; v[4]=bq.x; v[5]=bq.y; v[6]=bq.z; v[7]=bq.w;
            } else if (c0 >= 1024 && c0 < 1128) {
                const float* src = dWhh + r * 101;
#pragma unroll
                for (int u = 0; u < 8; ++u) { int cc = c0 + u; if (cc < 1125) v[u] = src[cc - 1024]; }
            }
        }
        bf16x8 o;
#pragma unroll
        for (int u = 0; u < 8; ++u) o[u] = (bf16_t)v[u];
        *(bf16x8*)(Wdec + (size_t)row * 1152 + c0) = o;
    } else {
        int idx = (b - 12672) * 256 + threadIdx.x;
        if (idx < 16384) {
            int l = idx >> 12, p = idx & 4095;
            int g = (p >> 4) & 3, e = ((p >> 6) << 4) + (p & 15);
            bse[idx] = (e < 1000) ? (ebih[l * 4000 + g * 1000 + e] + ebhh[l * 4000 + g * 1000 + e]) : 0.0f;
        } else {
            int k = idx - 16384;
            int l = k >> 9, p = k & 511;
            int g = (p >> 4) & 3, e = ((p >> 6) << 4) + (p & 15);
            bsd[k] = (e < 101) ? (dbih[l * 404 + g * 101 + e] + dbhh[l * 404 + g * 101 + e]) : 0.0f;
        }
    }
}

extern "C" void kernel_launch(void* const* d_in, const int* in_sizes, int n_in,
                              void* d_out, int out_size, void* d_ws, size_t ws_size,
                              hipStream_t stream)
{
    (void)in_sizes; (void)n_in; (void)out_size; (void)ws_size;
    const float* x    = (const float*)d_in[0];
    const float* eWih = (const float*)d_in[1];
    const float* eWhh = (const float*)d_in[2];
    const float* ebih = (const float*)d_in[3];
    const float* ebhh = (const float*)d_in[4];
    const float* dWih = (const float*)d_in[5];
    const float* dWhh = (const float*)d_in[6];
    const float* dbih = (const float*)d_in[7];
    const float* dbhh = (const float*)d_in[8];

    char* ws = (char*)d_ws;
    bf16_t* Aenc = (bf16_t*)(ws);                 // 4096*1152*2   =  9,437,184
    bf16_t* Wenc = (bf16_t*)(ws + 9437184);       // 4*4096*1152*2 = 37,748,736
    bf16_t* Adec = (bf16_t*)(ws + 47185920);      //                  9,437,184
    bf16_t* Wdec = (bf16_t*)(ws + 56623104);      // 4*512*1152*2  =  4,718,592
    float*  bse  = (float*) (ws + 61341696);      // 4*4096*4      =     65,536
    float*  bsd  = (float*) (ws + 61407232);      // 4*512*4       =      8,192
    float*  cenc = (float*) (ws + 61415424);      // 4096*1024*4   = 16,777,216  (end 78,192,640)

    pack_all<<<12744, 256, 0, stream>>>(x, eWih, eWhh, ebih, ebhh, dWih, dWhh, dbih, dbhh,
                                        Aenc, Wenc, Wdec, bse, bsd);

    // Encoder: 4 layers, 2-barrier BM=128 kernel (grid 32x32 = 1024 blocks,
    // 4 blocks/CU). Layer 0: h == 0 -> K=128 (x part only), czero=1.
    for (int l = 0; l < 4; ++l) {
        gemm_lstm<128><<<dim3(32, 32), 256, 0, stream>>>(
            Aenc, Wenc + (size_t)l * 4096 * 1152, bse + l * 4096,
            cenc, 1024,
            (l < 3) ? Aenc : Adec, 1152, (l < 3) ? 128 : 0,
            (l == 0) ? 128 : 1152, 1152, 1152, (l == 3) ? 1 : 0, (l == 0) ? 1 : 0);
    }

    // Fully-fused decoder: Z in registers + 4 recurrent layers + log_softmax.
    // grid 128 x 512 threads (32 rows/block); replaces Z-GEMM + dec_fused.
    dec_fused2<<<128, 512, 0, stream>>>(Adec, Wdec, bsd, (float*)d_out);
}

// Round 6
// 320.647 us; speedup vs baseline: 1.3739x; 1.3739x over previous
//
#include <hip/hip_runtime.h>
#include <cstdint>
#include <cstddef>
#include <cmath>

typedef __bf16 bf16_t;
typedef __bf16 bf16x8 __attribute__((ext_vector_type(8)));
typedef float floatx4 __attribute__((ext_vector_type(4)));

#define AS1 __attribute__((address_space(1)))
#define AS3 __attribute__((address_space(3)))

__device__ __forceinline__ void gload_lds16(const bf16_t* g, bf16_t* l) {
    __builtin_amdgcn_global_load_lds((AS1 void*)(uintptr_t)(g), (AS3 void*)(l), 16, 0, 0);
}

__device__ __forceinline__ float sigf(float x) { return 1.0f / (1.0f + __expf(-x)); }
__device__ __forceinline__ float tanhfast(float x) { return 1.0f - 2.0f / (__expf(2.0f * x) + 1.0f); }

// ------------- Fused GEMM + LSTM cell / gate-precompute (templated) -------------
// gates(M x N) = A(M,K) @ W(N,K)^T + bias(N).
// Weight rows packed gate-interleaved: lane's acc[i][0..3] are the 4 gates
// (i,f,g,o) of element e = ((n0+wn)>>2)+(lane&15)  (per 512-wide layer block).
// LDS XOR swizzle: physical 16B chunk = logical_kchunk ^ (row&7); staging keeps
// the linear base+lane*16 global_load_lds dest by permuting the per-lane
// *global* source address. Proven 2-barrier m97-structure (51 us/enc-layer,
// 4 blocks/CU). R2's 8-phase port and R5's stream-W-from-L2 decoder both
// regressed (lockstep waves / latency-bound) and stay reverted.
// MODE 0: LSTM-cell epilogue (encoder). czero=1 skips the c load (layer 0).
// MODE 1: gate-packed Z write: float4 {i,f,g,o}(t,e) -> Zp[t*512 + l*128 + e]
//         (l = layer block n>>9). Vector 16B stores, coalesced per 16-lane row.
template<int BM, int MODE>
__global__ __launch_bounds__(256, 4)
void gemm_lstm(const bf16_t* __restrict__ A, const bf16_t* __restrict__ B,
               const float* __restrict__ bias,
               float* __restrict__ zout,
               float* __restrict__ c, int EP,
               bf16_t* __restrict__ hb, int ldH, int hoff,
               int K, int ldA, int ldB, int relu, int czero)
{
    constexpr int AI = BM / 32;          // i-frags per wave = A-chunks per thread
    __shared__ bf16_t As[BM * 64];
    __shared__ bf16_t Bs[128 * 64];
    const int tid  = threadIdx.x;
    const int lane = tid & 63;
    const int w    = tid >> 6;
    const int wm   = (w & 1) * (BM / 2);
    const int wn   = (w >> 1) * 64;
    const int m0   = blockIdx.y * BM;
    const int n0   = blockIdx.x * 128;

    floatx4 zero = {0.0f, 0.0f, 0.0f, 0.0f};
    floatx4 acc[AI][4];
#pragma unroll
    for (int i = 0; i < AI; ++i)
#pragma unroll
        for (int j = 0; j < 4; ++j) acc[i][j] = zero;

    const int srow = lane >> 3;                 // staging row-in-chunk 0..7
    const int sk   = ((lane & 7) ^ srow) * 8;   // swizzled k-chunk (elements)
    const int fr   = lane & 15;                 // fragment row
    const int fx   = fr & 7;                    // read-side xor key

    const bf16_t* Ag = A + (size_t)(m0 + srow) * ldA + sk;
    const bf16_t* Bg = B + (size_t)(n0 + srow) * ldB + sk;

    for (int k0 = 0; k0 < K; k0 += 64) {
        __syncthreads();
#pragma unroll
        for (int j = 0; j < AI; ++j) {
            int r0 = (w * AI + j) * 8;
            gload_lds16(Ag + (size_t)r0 * ldA + k0, As + r0 * 64 + lane * 8);
        }
#pragma unroll
        for (int j = 0; j < 4; ++j) {
            int r0 = (w * 4 + j) * 8;
            gload_lds16(Bg + (size_t)r0 * ldB + k0, Bs + r0 * 64 + lane * 8);
        }
        __syncthreads();
#pragma unroll
        for (int kk = 0; kk < 64; kk += 32) {
            const int pc = ((((kk >> 3) + (lane >> 4)) ^ fx) << 3);
            bf16x8 af[AI], bfr[4];
#pragma unroll
            for (int i = 0; i < AI; ++i)
                af[i] = *(const bf16x8*)(As + (wm + i * 16 + fr) * 64 + pc);
#pragma unroll
            for (int j = 0; j < 4; ++j)
                bfr[j] = *(const bf16x8*)(Bs + (wn + j * 16 + fr) * 64 + pc);
#pragma unroll
            for (int i = 0; i < AI; ++i)
#pragma unroll
                for (int j = 0; j < 4; ++j)
                    acc[i][j] = __builtin_amdgcn_mfma_f32_16x16x32_bf16(af[i], bfr[j], acc[i][j], 0, 0, 0);
        }
    }

    // Epilogue. C/D layout: col = lane&15, row = (lane>>4)*4 + reg.
    const int crow = (lane >> 4) * 4;
    const int ccol = lane & 15;
    const int nn   = n0 + wn;
    float bi[4];
#pragma unroll
    for (int j = 0; j < 4; ++j) bi[j] = bias[nn + j * 16 + ccol];

    if constexpr (MODE == 1) {
        // Gate-packed Z: one float4 per (t, e). Same f32 values/add order as
        // the scalar path -> numerics unchanged.
        const int lz = nn >> 9;
        const int ez = ((nn & 511) >> 6) * 16 + ccol;
#pragma unroll
        for (int i = 0; i < AI; ++i) {
#pragma unroll
            for (int r = 0; r < 4; ++r) {
                int t = m0 + wm + i * 16 + crow + r;
                float4 g4;
                g4.x = acc[i][0][r] + bi[0];
                g4.y = acc[i][1][r] + bi[1];
                g4.z = acc[i][2][r] + bi[2];
                g4.w = acc[i][3][r] + bi[3];
                *(float4*)(zout + ((size_t)t * 512 + lz * 128 + ez) * 4) = g4;
            }
        }
        return;
    }

    const int e = (nn >> 2) + ccol;
#pragma unroll
    for (int i = 0; i < AI; ++i) {
#pragma unroll
        for (int r = 0; r < 4; ++r) {
            int t = m0 + wm + i * 16 + crow + r;
            float g0 = acc[i][0][r] + bi[0];
            float g1 = acc[i][1][r] + bi[1];
            float g2 = acc[i][2][r] + bi[2];
            float g3 = acc[i][3][r] + bi[3];
            size_t cix = (size_t)t * EP + e;
            float cold = 0.0f;
            if (!czero) cold = c[cix];
            float cv = sigf(g1) * cold + sigf(g0) * tanhfast(g2);
            c[cix] = cv;
            float hv = sigf(g3) * tanhfast(cv);
            if (relu) hv = fmaxf(hv, 0.0f);
            hb[(size_t)t * ldH + hoff + e] = (bf16_t)hv;
        }
    }
}

// ============ Fused decoder chain: 4 recurrent layers + log_softmax ============
// R4's verified dec_fused, upgraded: 8 waves (512 thr) instead of 4, and Z
// read as coalesced float4 gate-vectors (16 loads/lane total vs 128 strided
// scalars). Each block owns 16 rows, runs all 4 layers internally:
//   layer l gates(16 x 512) = Zp-slice (precomputed, incl. bias) + h @ Whh_l^T
// Wave w owns packed n-slice [w*64, w*64+64): gate j frag at row
// l*512 + w*64 + j*16 + fr -> gate = j, e = w*16 + fr (matches Zp layout).
// h via LDS bf16 (pad-136: <=2-way banks on frag reads = free); c in regs;
// Whh B-frags straight from global (Wdec 4.7 MB, L2/L3-hot). Layer-3 h ->
// f32 LDS -> log_softmax over 101 cols -> out. Numerics identical to R4.
__global__ __launch_bounds__(512)
void dec_fused3(const float* __restrict__ Zp, const bf16_t* __restrict__ Wd,
                float* __restrict__ out)
{
    __shared__ bf16_t hB[16 * 136];
    __shared__ float  hS[16 * 132];
    const int tid  = threadIdx.x;
    const int lane = tid & 63;
    const int w    = tid >> 6;         // 0..7
    const int m0   = blockIdx.x * 16;
    const int fr   = lane & 15;
    const int ksl  = (lane >> 4) * 8;
    const int crow = (lane >> 4) * 4;

    float cst[4];
    floatx4 zerov = {0.0f, 0.0f, 0.0f, 0.0f};

    for (int l = 0; l < 4; ++l) {
        // Z prefetch (independent of hB -> scheduler hoists above MFMA waits)
        float4 z4[4];
#pragma unroll
        for (int r = 0; r < 4; ++r)
            z4[r] = *(const float4*)(Zp +
                ((size_t)(m0 + crow + r) * 512 + l * 128 + w * 16 + fr) * 4);

        floatx4 acc[4];
#pragma unroll
        for (int j = 0; j < 4; ++j) acc[j] = zerov;

        if (l > 0) {
            // acc += h(16x128) @ dWhh_l^T  (K=128, 4 kk-steps)
#pragma unroll
            for (int kk = 0; kk < 4; ++kk) {
                bf16x8 a = *(const bf16x8*)(hB + fr * 136 + kk * 32 + ksl);
#pragma unroll
                for (int j = 0; j < 4; ++j) {
                    bf16x8 b = *(const bf16x8*)(Wd +
                        (size_t)(l * 512 + w * 64 + j * 16 + fr) * 1152 + 1024 + kk * 32 + ksl);
                    acc[j] = __builtin_amdgcn_mfma_f32_16x16x32_bf16(a, b, acc[j], 0, 0, 0);
                }
            }
        }
        __syncthreads();   // hB reads complete before overwrite below

#pragma unroll
        for (int r = 0; r < 4; ++r) {
            float g0 = acc[0][r] + z4[r].x;
            float g1 = acc[1][r] + z4[r].y;
            float g2 = acc[2][r] + z4[r].z;
            float g3 = acc[3][r] + z4[r].w;
            float cold = (l == 0) ? 0.0f : cst[r];
            float cv = sigf(g1) * cold + sigf(g0) * tanhfast(g2);
            cst[r] = cv;
            float hv = sigf(g3) * tanhfast(cv);
            int row = crow + r;
            int e   = w * 16 + fr;
            if (l < 3) hB[row * 136 + e] = (bf16_t)hv;
            else       hS[row * 132 + e] = hv;
        }
        __syncthreads();   // h fully written before next layer / softmax
    }

    // fused log_softmax over 101 valid cols: wave w handles rows 2w, 2w+1
#pragma unroll
    for (int rr = 0; rr < 2; ++rr) {
        int row = w * 2 + rr;
        const float* hr = hS + row * 132;
        float v1 = (lane < 101)      ? hr[lane]      : -INFINITY;
        float v2 = (lane + 64 < 101) ? hr[lane + 64] : -INFINITY;
        float m = fmaxf(v1, v2);
#pragma unroll
        for (int off = 32; off > 0; off >>= 1) m = fmaxf(m, __shfl_down(m, off));
        m = __shfl(m, 0);
        float ev = ((lane < 101) ? __expf(v1 - m) : 0.0f)
                 + ((lane + 64 < 101) ? __expf(v2 - m) : 0.0f);
#pragma unroll
        for (int off = 32; off > 0; off >>= 1) ev += __shfl_down(ev, off);
        float lse = m + __logf(__shfl(ev, 0));
        float* orow = out + (size_t)(m0 + row) * 101;
        if (lane < 101)      orow[lane]      = v1 - lse;
        if (lane + 64 < 101) orow[lane + 64] = v2 - lse;
    }
}

// ---------------- Packing (interleaved-gate layout, vectorized) ----------------
// A_enc (4096 x 1152 bf16): [x(0:101) pad(101:128) h(128:1152)]
// A_dec (4096 x 1152 bf16): [enc(0:1024) h-slot unused]
// One kernel, block-range dispatched (all outputs disjoint):
//   [0,     9216) : W_enc  (16384 rows * 144 groups of 8)
//   [9216, 11520) : A_enc x+zero fill (4096 rows * 144 groups)
//   [11520,12672) : W_dec  (2048 rows * 144 groups)
//   [12672,12744) : biases (16384 enc + 2048 dec)
// Layer-0 K-trim + czero keep every buffer write-before-read
// (ws re-poisoned 0xAA every call).
__global__ void pack_all(const float* __restrict__ x,
                         const float* __restrict__ eWih, const float* __restrict__ eWhh,
                         const float* __restrict__ ebih, const float* __restrict__ ebhh,
                         const float* __restrict__ dWih, const float* __restrict__ dWhh,
                         const float* __restrict__ dbih, const float* __restrict__ dbhh,
                         bf16_t* __restrict__ Aenc, bf16_t* __restrict__ Wenc,
                         bf16_t* __restrict__ Wdec,
                         float* __restrict__ bse, float* __restrict__ bsd)
{
    const int b = blockIdx.x;
    if (b < 9216) {
        int gid = b * 256 + threadIdx.x;
        int row = gid / 144, grp = gid - row * 144;
        int l = row >> 12, p = row & 4095;
        int g = (p >> 4) & 3, e = ((p >> 6) << 4) + (p & 15);
        int c0 = grp * 8;
        float v[8];
#pragma unroll
        for (int u = 0; u < 8; ++u) v[u] = 0.0f;
        if (e < 1000) {
            size_t r = (size_t)l * 4000 + g * 1000 + e;
            if (c0 >= 128 && c0 < 1128) {
                const float* src = eWhh + r * 1000 + (c0 - 128);
                float4 a = *(const float4*)src;
                float4 bq = *(const float4*)(src + 4);
                v[0]=a.x; v[1]=a.y; v[2]=a.z; v[3]=a.w; v[4]=bq.x; v[5]=bq.y; v[6]=bq.z; v[7]=bq.w;
            } else if (c0 < 128) {
                const float* src = eWih + r * 101;
#pragma unroll
                for (int u = 0; u < 8; ++u) { int cc = c0 + u; if (cc < 101) v[u] = src[cc]; }
            }
        }
        bf16x8 o;
#pragma unroll
        for (int u = 0; u < 8; ++u) o[u] = (bf16_t)v[u];
        *(bf16x8*)(Wenc + (size_t)row * 1152 + c0) = o;
    } else if (b < 11520) {
        int gid = (b - 9216) * 256 + threadIdx.x;
        int row = gid / 144, grp = gid - row * 144;
        int c0  = grp * 8;
        float v[8];
#pragma unroll
        for (int u = 0; u < 8; ++u) v[u] = 0.0f;
        if (c0 < 101) {
            const float* src = x + (size_t)row * 101;
#pragma unroll
            for (int u = 0; u < 8; ++u) { int cc = c0 + u; if (cc < 101) v[u] = src[cc]; }
        }
        bf16x8 o;
#pragma unroll
        for (int u = 0; u < 8; ++u) o[u] = (bf16_t)v[u];
        *(bf16x8*)(Aenc + (size_t)row * 1152 + c0) = o;
    } else if (b < 12672) {
        int gid = (b - 11520) * 256 + threadIdx.x;
        int row = gid / 144, grp = gid - row * 144;
        int l = row >> 9, p = row & 511;
        int g = (p >> 4) & 3, e = ((p >> 6) << 4) + (p & 15);
        int c0 = grp * 8;
        float v[8];
#pragma unroll
        for (int u = 0; u < 8; ++u) v[u] = 0.0f;
        if (e < 101) {
            size_t r = (size_t)l * 404 + g * 101 + e;
            if (c0 < 1000) {
                const float* src = dWih + r * 1000 + c0;
                float4 a = *(const float4*)src;
                float4 bq = *(const float4*)(src + 4);
                v[0]=a.x; v[1]=a.y; v[2]=a.z; v[3]=a.w; v[4]=bq.x; v[5]=bq.y; v[6]=bq.z; v[7]=bq.w;
            } else if (c0 >= 1024 && c0 < 1128) {
                const float* src = dWhh + r * 101;
#pragma unroll
                for (int u = 0; u < 8; ++u) { int cc = c0 + u; if (cc < 1125) v[u] = src[cc - 1024]; }
            }
        }
        bf16x8 o;
#pragma unroll
        for (int u = 0; u < 8; ++u) o[u] = (bf16_t)v[u];
        *(bf16x8*)(Wdec + (size_t)row * 1152 + c0) = o;
    } else {
        int idx = (b - 12672) * 256 + threadIdx.x;
        if (idx < 16384) {
            int l = idx >> 12, p = idx & 4095;
            int g = (p >> 4) & 3, e = ((p >> 6) << 4) + (p & 15);
            bse[idx] = (e < 1000) ? (ebih[l * 4000 + g * 1000 + e] + ebhh[l * 4000 + g * 1000 + e]) : 0.0f;
        } else {
            int k = idx - 16384;
            int l = k >> 9, p = k & 511;
            int g = (p >> 4) & 3, e = ((p >> 6) << 4) + (p & 15);
            bsd[k] = (e < 101) ? (dbih[l * 404 + g * 101 + e] + dbhh[l * 404 + g * 101 + e]) : 0.0f;
        }
    }
}

extern "C" void kernel_launch(void* const* d_in, const int* in_sizes, int n_in,
                              void* d_out, int out_size, void* d_ws, size_t ws_size,
                              hipStream_t stream)
{
    (void)in_sizes; (void)n_in; (void)out_size; (void)ws_size;
    const float* x    = (const float*)d_in[0];
    const float* eWih = (const float*)d_in[1];
    const float* eWhh = (const float*)d_in[2];
    const float* ebih = (const float*)d_in[3];
    const float* ebhh = (const float*)d_in[4];
    const float* dWih = (const float*)d_in[5];
    const float* dWhh = (const float*)d_in[6];
    const float* dbih = (const float*)d_in[7];
    const float* dbhh = (const float*)d_in[8];

    char* ws = (char*)d_ws;
    bf16_t* Aenc = (bf16_t*)(ws);                 // 4096*1152*2   =  9,437,184
    bf16_t* Wenc = (bf16_t*)(ws + 9437184);       // 4*4096*1152*2 = 37,748,736
    bf16_t* Adec = (bf16_t*)(ws + 47185920);      //                  9,437,184
    bf16_t* Wdec = (bf16_t*)(ws + 56623104);      // 4*512*1152*2  =  4,718,592
    float*  bse  = (float*) (ws + 61341696);      // 4*4096*4      =     65,536
    float*  bsd  = (float*) (ws + 61407232);      // 4*512*4       =      8,192
    float*  cenc = (float*) (ws + 61415424);      // 4096*1024*4   = 16,777,216  (end 78,192,640)
    // Zp (gate-packed decoder gates, 4096 x 512 float4 = 33,554,432 B) aliases
    // the Wenc region (37.7 MB), dead after encoder layer 3 reads it.
    float*  Zp   = (float*)(ws + 9437184);

    pack_all<<<12744, 256, 0, stream>>>(x, eWih, eWhh, ebih, ebhh, dWih, dWhh, dbih, dbhh,
                                        Aenc, Wenc, Wdec, bse, bsd);

    // Encoder: 4 layers, 2-barrier BM=128 kernel (grid 32x32 = 1024 blocks,
    // 4 blocks/CU). Layer 0: h == 0 -> K=128 (x part only), czero=1.
    for (int l = 0; l < 4; ++l) {
        gemm_lstm<128, 0><<<dim3(32, 32), 256, 0, stream>>>(
            Aenc, Wenc + (size_t)l * 4096 * 1152, bse + l * 4096,
            nullptr,
            cenc, 1024,
            (l < 3) ? Aenc : Adec, 1152, (l < 3) ? 128 : 0,
            (l == 0) ? 128 : 1152, 1152, 1152, (l == 3) ? 1 : 0, (l == 0) ? 1 : 0);
    }

    // Decoder gate precompute (layer-independent 89% of decoder FLOPs):
    //   Zp[t, l*128+e] (float4 gates) = enc @ dWih^T + b  (M=4096, N=2048, K=1024)
    // grid(16,32) = 512 blocks. Distinct template tag -> distinct kernel name
    // in rocprof for attribution.
    gemm_lstm<128, 1><<<dim3(16, 32), 256, 0, stream>>>(
        Adec, Wdec, bsd,
        Zp,
        nullptr, 0,
        nullptr, 0, 0,
        1024, 1152, 1152, 0, 0);

    // Fused decoder chain: 4 recurrent layers (K=128; layer 0 pure cell on Z)
    // + log_softmax. 256 blocks x 512 thr (8 waves), vectorized Z reads.
    dec_fused3<<<256, 512, 0, stream>>>(Zp, Wdec, (float*)d_out);
}